// Round 4
// baseline (303.173 us; speedup 1.0000x reference)
//
#include <hip/hip_runtime.h>
#include <hip/hip_bf16.h>
#include <math.h>

// GCN 3-layer inference. N=100000, E=3200000, feats 128->4->2->1.
// R4: no global scatter, no within-bucket sort, zero device atomics.
//  k_part   : per-4096-edge block LDS counting-sort by bucket(dst>>8),
//             coalesced write to block-contiguous slab + per-(blk,bin) offsets.
//  k_degree : per-bucket: gather slab segments -> LDS, per-node degree hist,
//             write dinv + consolidated bucket-contiguous edge list pairs2.
//  k_agg*   : stream pairs2 coalesced, gather hs[src] (L2), LDS float-atomic
//             accumulate (padded stride -> ~2-way banks), fused epilogue.
// Edge pack: p = src | (dst&255)<<17   (src < 2^17 since N <= 131072).

#define TPB 256
#define CHUNK 4096
#define EPT (CHUNK / TPB)   // 16 edges/thread in k_part
#define SLAB2 9216          // per-bucket pairs2 capacity (mean 8184, +11 sigma)
#define NSMAX 1024          // max slab count

// ---- k_part: local counting sort of one 4096-edge chunk ----
__global__ __launch_bounds__(TPB) void k_part(
    const int* __restrict__ src, const int* __restrict__ dst,
    unsigned int* __restrict__ slab, int* __restrict__ lstart,
    int NB, int NBP, int E)
{
    __shared__ int hist[512];
    __shared__ int s[TPB];
    __shared__ unsigned int sorted[CHUNK];
    int t = threadIdx.x;
    int base = blockIdx.x * CHUNK;
    int n = min(CHUNK, E - base);
    hist[t] = 0; hist[t + 256] = 0;
    __syncthreads();
    unsigned int meta[EPT];   // d<<13 | lp   (d<2^17, lp<4096)
#pragma unroll
    for (int k = 0; k < EPT; ++k) {
        int li = k * TPB + t;
        if (li < n) {
            int d = dst[base + li];
            int lp = atomicAdd(&hist[d >> 8], 1);
            meta[k] = ((unsigned)d << 13) | (unsigned)lp;
        } else meta[k] = 0xFFFFFFFFu;
    }
    __syncthreads();
    // exclusive scan hist[0..511] (chunked Hillis-Steele)
    int run = 0;
    for (int cb = 0; cb < 512; cb += TPB) {
        int v = hist[cb + t];
        s[t] = v;
        __syncthreads();
        int x = v;
        for (int d = 1; d < TPB; d <<= 1) {
            int y = (t >= d) ? s[t - d] : 0;
            __syncthreads();
            x += y; s[t] = x;
            __syncthreads();
        }
        hist[cb + t] = run + (x - v);
        run += s[TPB - 1];
        __syncthreads();
    }
    // scatter into LDS sorted order (reload src coalesced)
#pragma unroll
    for (int k = 0; k < EPT; ++k) {
        if (meta[k] != 0xFFFFFFFFu) {
            unsigned m = meta[k];
            int d = (int)(m >> 13);
            int lp = (int)(m & 0x1FFFu);
            unsigned p = (unsigned)src[base + k * TPB + t] | ((unsigned)(d & 255) << 17);
            sorted[hist[d >> 8] + lp] = p;
        }
    }
    __syncthreads();
    // coalesced slab write (full chunk; tail garbage never read) + offsets row
    const uint4* s4 = (const uint4*)sorted;
    uint4* g4 = (uint4*)(slab + (size_t)base);
    for (int i = t; i < CHUNK / 4; i += TPB) g4[i] = s4[i];
    for (int i = t; i < NBP; i += TPB)
        lstart[(size_t)blockIdx.x * NBP + i] = (i < NB) ? hist[i] : n;
}

// ---- k_degree: consolidate bucket edges + per-node degree -> dinv ----
__global__ __launch_bounds__(TPB) void k_degree(
    const unsigned int* __restrict__ slab, const int* __restrict__ lstart,
    unsigned int* __restrict__ pairs2, int* __restrict__ bcnt,
    float* __restrict__ dinv, int NS, int NBP, int N)
{
    __shared__ unsigned int pl[SLAB2];
    __shared__ int slen[NSMAX];
    __shared__ int s[TPB];
    __shared__ int c[TPB];
    int t = threadIdx.x, b = blockIdx.x;
    c[t] = 0;
    int stv[NSMAX / TPB], lenv[NSMAX / TPB];
#pragma unroll
    for (int ci = 0; ci < NSMAX / TPB; ++ci) {
        int j = ci * TPB + t;
        int st = 0, len = 0;
        if (j < NS) {
            st = lstart[(size_t)j * NBP + b];
            len = lstart[(size_t)j * NBP + b + 1] - st;
        }
        stv[ci] = st; lenv[ci] = len;
        slen[j] = len;
    }
    __syncthreads();
    // exclusive scan slen[0..NSMAX)
    int run = 0;
    for (int cb = 0; cb < NSMAX; cb += TPB) {
        int v = slen[cb + t];
        s[t] = v;
        __syncthreads();
        int x = v;
        for (int d = 1; d < TPB; d <<= 1) {
            int y = (t >= d) ? s[t - d] : 0;
            __syncthreads();
            x += y; s[t] = x;
            __syncthreads();
        }
        slen[cb + t] = run + (x - v);
        run += s[TPB - 1];
        __syncthreads();
    }
    int total = min(run, SLAB2);
    // copy segments into LDS at scanned offsets
#pragma unroll
    for (int ci = 0; ci < NSMAX / TPB; ++ci) {
        int j = ci * TPB + t;
        if (j < NS && lenv[ci] > 0) {
            int lo = slen[j];
            const unsigned int* sp = slab + (size_t)j * CHUNK + stv[ci];
            for (int k = 0; k < lenv[ci]; ++k) {
                if (lo + k >= SLAB2) break;
                pl[lo + k] = sp[k];
            }
        }
    }
    __syncthreads();
    // per-node degree (LDS int atomics, random banks)
    for (int i = t; i < total; i += TPB) atomicAdd(&c[(pl[i] >> 17) & 255], 1);
    __syncthreads();
    // coalesced consolidated write + dinv
    unsigned int* p2 = pairs2 + (size_t)b * SLAB2;
    for (int i = t; i < total; i += TPB) p2[i] = pl[i];
    if (t == 0) bcnt[b] = total;
    int v = (b << 8) + t;
    if (v < N) dinv[v] = rsqrtf((float)(c[t] + 1));
}

// ---- Layer-1 GEMM (128->4): hs1 = dinv * (x@W1). Quad-per-node. ----
__global__ __launch_bounds__(TPB) void k_node1(
    const float* __restrict__ x, const float* __restrict__ W1,
    const float* __restrict__ dinv, float* __restrict__ hs1, int n) {
    __shared__ float Ws[512];  // W1 [128][4] row-major
    for (int i = threadIdx.x; i < 512; i += TPB) Ws[i] = W1[i];
    __syncthreads();
    int t = blockIdx.x * TPB + threadIdx.x;
    int v = t >> 2, p = t & 3;
    if (v >= n) return;
    const float4* xr = (const float4*)(x + (size_t)v * 128);
    float a0 = 0.f, a1 = 0.f, a2 = 0.f, a3 = 0.f;
#pragma unroll
    for (int i = 0; i < 8; ++i) {
        int c = p + i * 4;
        float4 xx = xr[c];
        const float* w = &Ws[c * 16];
        a0 += xx.x * w[0] + xx.y * w[4] + xx.z * w[8]  + xx.w * w[12];
        a1 += xx.x * w[1] + xx.y * w[5] + xx.z * w[9]  + xx.w * w[13];
        a2 += xx.x * w[2] + xx.y * w[6] + xx.z * w[10] + xx.w * w[14];
        a3 += xx.x * w[3] + xx.y * w[7] + xx.z * w[11] + xx.w * w[15];
    }
    a0 += __shfl_xor(a0, 1); a0 += __shfl_xor(a0, 2);
    a1 += __shfl_xor(a1, 1); a1 += __shfl_xor(a1, 2);
    a2 += __shfl_xor(a2, 1); a2 += __shfl_xor(a2, 2);
    a3 += __shfl_xor(a3, 1); a3 += __shfl_xor(a3, 2);
    if (p == 0) {
        float di = dinv[v];
        ((float4*)hs1)[v] = make_float4(di * a0, di * a1, di * a2, di * a3);
    }
}

// ---- agg1: stream pairs2, LDS accumulate (stride 5), relu+W2 -> hs2 ----
__global__ __launch_bounds__(TPB) void k_agg1(
    const unsigned int* __restrict__ pairs2, const int* __restrict__ bcnt,
    const float* __restrict__ hs1, const float* __restrict__ dinv,
    const float* __restrict__ b1, const float* __restrict__ W2,
    float* __restrict__ hs2, int N)
{
    __shared__ float acc[TPB * 5];
    int t = threadIdx.x, b = blockIdx.x;
#pragma unroll
    for (int k = 0; k < 5; ++k) acc[k * TPB + t] = 0.f;
    __syncthreads();
    int cnt = bcnt[b];
    const unsigned int* p2 = pairs2 + (size_t)b * SLAB2;
    for (int i = t; i < cnt; i += TPB) {
        unsigned p = p2[i];
        int sidx = (int)(p & 0x1FFFFu);
        int d = (int)((p >> 17) & 255u);
        float4 h = ((const float4*)hs1)[sidx];
        float* a = &acc[d * 5];
        atomicAdd(a + 0, h.x); atomicAdd(a + 1, h.y);
        atomicAdd(a + 2, h.z); atomicAdd(a + 3, h.w);
    }
    __syncthreads();
    int v = (b << 8) + t;
    if (v < N) {
        float4 hv = ((const float4*)hs1)[v];
        float di = dinv[v];
        float o0 = fmaxf(di * (acc[t * 5 + 0] + hv.x) + b1[0], 0.f);
        float o1 = fmaxf(di * (acc[t * 5 + 1] + hv.y) + b1[1], 0.f);
        float o2 = fmaxf(di * (acc[t * 5 + 2] + hv.z) + b1[2], 0.f);
        float o3 = fmaxf(di * (acc[t * 5 + 3] + hv.w) + b1[3], 0.f);
        float h0 = o0 * W2[0] + o1 * W2[2] + o2 * W2[4] + o3 * W2[6];
        float h1 = o0 * W2[1] + o1 * W2[3] + o2 * W2[5] + o3 * W2[7];
        ((float2*)hs2)[v] = make_float2(di * h0, di * h1);
    }
}

// ---- agg2: stride 3, relu+W3 -> hs3 ----
__global__ __launch_bounds__(TPB) void k_agg2(
    const unsigned int* __restrict__ pairs2, const int* __restrict__ bcnt,
    const float* __restrict__ hs2, const float* __restrict__ dinv,
    const float* __restrict__ b2, const float* __restrict__ W3,
    float* __restrict__ hs3, int N)
{
    __shared__ float acc[TPB * 3];
    int t = threadIdx.x, b = blockIdx.x;
#pragma unroll
    for (int k = 0; k < 3; ++k) acc[k * TPB + t] = 0.f;
    __syncthreads();
    int cnt = bcnt[b];
    const unsigned int* p2 = pairs2 + (size_t)b * SLAB2;
    for (int i = t; i < cnt; i += TPB) {
        unsigned p = p2[i];
        int sidx = (int)(p & 0x1FFFFu);
        int d = (int)((p >> 17) & 255u);
        float2 h = ((const float2*)hs2)[sidx];
        float* a = &acc[d * 3];
        atomicAdd(a + 0, h.x); atomicAdd(a + 1, h.y);
    }
    __syncthreads();
    int v = (b << 8) + t;
    if (v < N) {
        float2 hv = ((const float2*)hs2)[v];
        float di = dinv[v];
        float o0 = fmaxf(di * (acc[t * 3 + 0] + hv.x) + b2[0], 0.f);
        float o1 = fmaxf(di * (acc[t * 3 + 1] + hv.y) + b2[1], 0.f);
        float h3 = o0 * W3[0] + o1 * W3[1];
        hs3[v] = di * h3;
    }
}

// ---- agg3: stride 1, sigmoid -> out ----
__global__ __launch_bounds__(TPB) void k_agg3(
    const unsigned int* __restrict__ pairs2, const int* __restrict__ bcnt,
    const float* __restrict__ hs3, const float* __restrict__ dinv,
    const float* __restrict__ b3, float* __restrict__ out, int N)
{
    __shared__ float acc[TPB];
    int t = threadIdx.x, b = blockIdx.x;
    acc[t] = 0.f;
    __syncthreads();
    int cnt = bcnt[b];
    const unsigned int* p2 = pairs2 + (size_t)b * SLAB2;
    for (int i = t; i < cnt; i += TPB) {
        unsigned p = p2[i];
        atomicAdd(&acc[(p >> 17) & 255u], hs3[p & 0x1FFFFu]);
    }
    __syncthreads();
    int v = (b << 8) + t;
    if (v < N) {
        float di = dinv[v];
        float agg = di * (acc[t] + hs3[v]) + b3[0];
        out[v] = 1.0f / (1.0f + __expf(-agg));
    }
}

extern "C" void kernel_launch(void* const* d_in, const int* in_sizes, int n_in,
                              void* d_out, int out_size, void* d_ws, size_t ws_size,
                              hipStream_t stream) {
    const float* x  = (const float*)d_in[0];
    const int* ei   = (const int*)d_in[1];
    const float* W1 = (const float*)d_in[2];
    const float* b1 = (const float*)d_in[3];
    const float* W2 = (const float*)d_in[4];
    const float* b2 = (const float*)d_in[5];
    const float* W3 = (const float*)d_in[6];
    const float* b3 = (const float*)d_in[7];
    float* out = (float*)d_out;

    const int N = in_sizes[0] / 128;
    const int E = in_sizes[1] / 2;
    const int* src = ei;
    const int* dst = ei + E;

    const int NS  = (E + CHUNK - 1) / CHUNK;  // slabs (782)
    const int NB  = (N + 255) >> 8;           // buckets (391)
    const int NBP = NB + 1;

    // ws carve (~28.9 MB). hs1/hs2/hs3 overlay the slab (freed after k_degree).
    char* w = (char*)d_ws;
    auto carve = [&](size_t bytes) { char* p = w; w += (bytes + 15) & ~(size_t)15; return p; };
    unsigned int* slab   = (unsigned int*)carve((size_t)NS * CHUNK * 4);
    int* lstart          = (int*)carve((size_t)NS * NBP * 4);
    unsigned int* pairs2 = (unsigned int*)carve((size_t)NB * SLAB2 * 4);
    int* bcnt            = (int*)carve((size_t)NB * 4);
    float* dinv          = (float*)carve((size_t)N * 4);
    float* hs1 = (float*)slab;                 // 4N floats (overlay)
    float* hs2 = hs1 + (size_t)4 * N;          // 2N
    float* hs3 = hs2 + (size_t)2 * N;          // N

    const int nbN4 = (4 * N + TPB - 1) / TPB;

    k_part  <<<NS, TPB, 0, stream>>>(src, dst, slab, lstart, NB, NBP, E);
    k_degree<<<NB, TPB, 0, stream>>>(slab, lstart, pairs2, bcnt, dinv, NS, NBP, N);
    k_node1 <<<nbN4, TPB, 0, stream>>>(x, W1, dinv, hs1, N);
    k_agg1  <<<NB, TPB, 0, stream>>>(pairs2, bcnt, hs1, dinv, b1, W2, hs2, N);
    k_agg2  <<<NB, TPB, 0, stream>>>(pairs2, bcnt, hs2, dinv, b2, W3, hs3, N);
    k_agg3  <<<NB, TPB, 0, stream>>>(pairs2, bcnt, hs3, dinv, b3, out, N);
}

// Round 5
// 217.288 us; speedup vs baseline: 1.3953x; 1.3953x over previous
//
#include <hip/hip_runtime.h>
#include <hip/hip_bf16.h>
#include <math.h>

// GCN 3-layer inference. N=100000, E=3200000, feats 128->4->2->1.
// R5 = R4's zero-device-atomic two-phase sort + R2's node-centric CSR gathers.
//  k_part   : per-4096-edge chunk LDS counting-sort by bucket(dst>>8),
//             coalesced slab write + per-(chunk,bin) offsets.
//  k_degree : per 256-node bucket: merge slab segments into LDS, per-node
//             count (LDS atomics), LDS scan -> counting-sort into dst-sorted
//             CSR ssrc (bucket-local region), write cnt/off/dinv.
//  k_node1  : 128->4 GEMM, hs1 = dinv * (x@W1)  (quad-per-node, shfl reduce).
//  k_gather*: 8 lanes per node walk the node's contiguous CSR segment,
//             gather hs[src] (L2-resident), shfl reduce, fused epilogue.
// Edge pack: p = src | (dst&255)<<17  (src < 2^17).

#define TPB 256
#define CHUNK 4096
#define EPT (CHUNK / TPB)
#define SLAB2 9216          // per-bucket CSR capacity (mean 8184, +11 sigma)
#define NSMAX 1024

// ---- k_part: local counting sort of one 4096-edge chunk ----
__global__ __launch_bounds__(TPB) void k_part(
    const int* __restrict__ src, const int* __restrict__ dst,
    unsigned int* __restrict__ slab, int* __restrict__ lstart,
    int NB, int NBP, int E)
{
    __shared__ int hist[512];
    __shared__ int s[TPB];
    __shared__ unsigned int sorted[CHUNK];
    int t = threadIdx.x;
    int base = blockIdx.x * CHUNK;
    int n = min(CHUNK, E - base);
    hist[t] = 0; hist[t + 256] = 0;
    __syncthreads();
    unsigned int meta[EPT];   // d<<13 | lp
#pragma unroll
    for (int k = 0; k < EPT; ++k) {
        int li = k * TPB + t;
        if (li < n) {
            int d = dst[base + li];
            int lp = atomicAdd(&hist[d >> 8], 1);
            meta[k] = ((unsigned)d << 13) | (unsigned)lp;
        } else meta[k] = 0xFFFFFFFFu;
    }
    __syncthreads();
    int run = 0;
    for (int cb = 0; cb < 512; cb += TPB) {
        int v = hist[cb + t];
        s[t] = v;
        __syncthreads();
        int x = v;
        for (int d = 1; d < TPB; d <<= 1) {
            int y = (t >= d) ? s[t - d] : 0;
            __syncthreads();
            x += y; s[t] = x;
            __syncthreads();
        }
        hist[cb + t] = run + (x - v);
        run += s[TPB - 1];
        __syncthreads();
    }
#pragma unroll
    for (int k = 0; k < EPT; ++k) {
        if (meta[k] != 0xFFFFFFFFu) {
            unsigned m = meta[k];
            int d = (int)(m >> 13);
            int lp = (int)(m & 0x1FFFu);
            unsigned p = (unsigned)src[base + k * TPB + t] | ((unsigned)(d & 255) << 17);
            sorted[hist[d >> 8] + lp] = p;
        }
    }
    __syncthreads();
    const uint4* s4 = (const uint4*)sorted;
    uint4* g4 = (uint4*)(slab + (size_t)base);
    for (int i = t; i < CHUNK / 4; i += TPB) g4[i] = s4[i];
    for (int i = t; i < NBP; i += TPB)
        lstart[(size_t)blockIdx.x * NBP + i] = (i < NB) ? hist[i] : n;
}

// ---- k_degree: merge bucket -> LDS, count, scan, sort -> CSR + dinv ----
__global__ __launch_bounds__(TPB) void k_degree(
    const unsigned int* __restrict__ slab, const int* __restrict__ lstart,
    int* __restrict__ ssrc, int* __restrict__ cnt, int* __restrict__ off,
    float* __restrict__ dinv, int NS, int NBP, int N)
{
    __shared__ unsigned int pl[SLAB2];
    __shared__ int slen[NSMAX];
    __shared__ int s[TPB];
    __shared__ int c[TPB];
    __shared__ int cur[TPB];
    int t = threadIdx.x, b = blockIdx.x;
    c[t] = 0;
    int stv[NSMAX / TPB], lenv[NSMAX / TPB];
#pragma unroll
    for (int ci = 0; ci < NSMAX / TPB; ++ci) {
        int j = ci * TPB + t;
        int st = 0, len = 0;
        if (j < NS) {
            st = lstart[(size_t)j * NBP + b];
            len = lstart[(size_t)j * NBP + b + 1] - st;
        }
        stv[ci] = st; lenv[ci] = len;
        slen[j] = len;
    }
    __syncthreads();
    // exclusive scan slen
    int run = 0;
    for (int cb = 0; cb < NSMAX; cb += TPB) {
        int v = slen[cb + t];
        s[t] = v;
        __syncthreads();
        int x = v;
        for (int d = 1; d < TPB; d <<= 1) {
            int y = (t >= d) ? s[t - d] : 0;
            __syncthreads();
            x += y; s[t] = x;
            __syncthreads();
        }
        slen[cb + t] = run + (x - v);
        run += s[TPB - 1];
        __syncthreads();
    }
    int total = min(run, SLAB2);
    // merge segments into LDS
#pragma unroll
    for (int ci = 0; ci < NSMAX / TPB; ++ci) {
        int j = ci * TPB + t;
        if (j < NS && lenv[ci] > 0) {
            int lo = slen[j];
            const unsigned int* sp = slab + (size_t)j * CHUNK + stv[ci];
            for (int k = 0; k < lenv[ci]; ++k) {
                if (lo + k >= SLAB2) break;
                pl[lo + k] = sp[k];
            }
        }
    }
    __syncthreads();
    // per-node degree
    for (int i = t; i < total; i += TPB) atomicAdd(&c[(pl[i] >> 17) & 255], 1);
    __syncthreads();
    // scan counts -> node-local offsets
    int cv = c[t];
    s[t] = cv;
    __syncthreads();
    int x = cv;
    for (int d = 1; d < TPB; d <<= 1) {
        int y = (t >= d) ? s[t - d] : 0;
        __syncthreads();
        x += y; s[t] = x;
        __syncthreads();
    }
    int excl = x - cv;
    int v = (b << 8) + t;
    if (v < N) {
        cnt[v] = cv;
        off[v] = b * SLAB2 + excl;
        dinv[v] = rsqrtf((float)(cv + 1));
    }
    cur[t] = excl;
    __syncthreads();
    // counting-sort scatter into bucket-local CSR region (L2-local 36KB)
    int* sb = ssrc + (size_t)b * SLAB2;
    for (int i = t; i < total; i += TPB) {
        unsigned p = pl[i];
        int pos = atomicAdd(&cur[(p >> 17) & 255], 1);
        sb[pos] = (int)(p & 0x1FFFFu);
    }
}

// ---- Layer-1 GEMM (128->4): hs1 = dinv * (x@W1). Quad-per-node. ----
__global__ __launch_bounds__(TPB) void k_node1(
    const float* __restrict__ x, const float* __restrict__ W1,
    const float* __restrict__ dinv, float* __restrict__ hs1, int n) {
    __shared__ float Ws[512];  // W1 [128][4] row-major
    for (int i = threadIdx.x; i < 512; i += TPB) Ws[i] = W1[i];
    __syncthreads();
    int t = blockIdx.x * TPB + threadIdx.x;
    int v = t >> 2, p = t & 3;
    if (v >= n) return;
    const float4* xr = (const float4*)(x + (size_t)v * 128);
    float a0 = 0.f, a1 = 0.f, a2 = 0.f, a3 = 0.f;
#pragma unroll
    for (int i = 0; i < 8; ++i) {
        int c = p + i * 4;
        float4 xx = xr[c];
        const float* w = &Ws[c * 16];
        a0 += xx.x * w[0] + xx.y * w[4] + xx.z * w[8]  + xx.w * w[12];
        a1 += xx.x * w[1] + xx.y * w[5] + xx.z * w[9]  + xx.w * w[13];
        a2 += xx.x * w[2] + xx.y * w[6] + xx.z * w[10] + xx.w * w[14];
        a3 += xx.x * w[3] + xx.y * w[7] + xx.z * w[11] + xx.w * w[15];
    }
    a0 += __shfl_xor(a0, 1); a0 += __shfl_xor(a0, 2);
    a1 += __shfl_xor(a1, 1); a1 += __shfl_xor(a1, 2);
    a2 += __shfl_xor(a2, 1); a2 += __shfl_xor(a2, 2);
    a3 += __shfl_xor(a3, 1); a3 += __shfl_xor(a3, 2);
    if (p == 0) {
        float di = dinv[v];
        ((float4*)hs1)[v] = make_float4(di * a0, di * a1, di * a2, di * a3);
    }
}

// ---- gathers: 8 lanes per node over contiguous CSR segment ----
__global__ __launch_bounds__(TPB) void k_gather1(
    const int* __restrict__ off, const int* __restrict__ cnt,
    const int* __restrict__ ssrc, const float* __restrict__ hs1,
    const float* __restrict__ dinv, const float* __restrict__ b1,
    const float* __restrict__ W2, float* __restrict__ hs2, int n) {
    int t = blockIdx.x * TPB + threadIdx.x;
    int v = t >> 3, p = t & 7;
    if (v >= n) return;
    int base = off[v], c = cnt[v];
    float4 acc = make_float4(0.f, 0.f, 0.f, 0.f);
    for (int i = p; i < c; i += 8) {
        int s = ssrc[base + i];
        float4 h = ((const float4*)hs1)[s];
        acc.x += h.x; acc.y += h.y; acc.z += h.z; acc.w += h.w;
    }
    acc.x += __shfl_xor(acc.x, 1); acc.x += __shfl_xor(acc.x, 2); acc.x += __shfl_xor(acc.x, 4);
    acc.y += __shfl_xor(acc.y, 1); acc.y += __shfl_xor(acc.y, 2); acc.y += __shfl_xor(acc.y, 4);
    acc.z += __shfl_xor(acc.z, 1); acc.z += __shfl_xor(acc.z, 2); acc.z += __shfl_xor(acc.z, 4);
    acc.w += __shfl_xor(acc.w, 1); acc.w += __shfl_xor(acc.w, 2); acc.w += __shfl_xor(acc.w, 4);
    if (p == 0) {
        float4 hv = ((const float4*)hs1)[v];
        float di = dinv[v];
        float o0 = fmaxf(di * (acc.x + hv.x) + b1[0], 0.f);
        float o1 = fmaxf(di * (acc.y + hv.y) + b1[1], 0.f);
        float o2 = fmaxf(di * (acc.z + hv.z) + b1[2], 0.f);
        float o3 = fmaxf(di * (acc.w + hv.w) + b1[3], 0.f);
        float h0 = o0 * W2[0] + o1 * W2[2] + o2 * W2[4] + o3 * W2[6];
        float h1 = o0 * W2[1] + o1 * W2[3] + o2 * W2[5] + o3 * W2[7];
        ((float2*)hs2)[v] = make_float2(di * h0, di * h1);
    }
}

__global__ __launch_bounds__(TPB) void k_gather2(
    const int* __restrict__ off, const int* __restrict__ cnt,
    const int* __restrict__ ssrc, const float* __restrict__ hs2,
    const float* __restrict__ dinv, const float* __restrict__ b2,
    const float* __restrict__ W3, float* __restrict__ hs3, int n) {
    int t = blockIdx.x * TPB + threadIdx.x;
    int v = t >> 3, p = t & 7;
    if (v >= n) return;
    int base = off[v], c = cnt[v];
    float2 acc = make_float2(0.f, 0.f);
    for (int i = p; i < c; i += 8) {
        int s = ssrc[base + i];
        float2 h = ((const float2*)hs2)[s];
        acc.x += h.x; acc.y += h.y;
    }
    acc.x += __shfl_xor(acc.x, 1); acc.x += __shfl_xor(acc.x, 2); acc.x += __shfl_xor(acc.x, 4);
    acc.y += __shfl_xor(acc.y, 1); acc.y += __shfl_xor(acc.y, 2); acc.y += __shfl_xor(acc.y, 4);
    if (p == 0) {
        float2 hv = ((const float2*)hs2)[v];
        float di = dinv[v];
        float o0 = fmaxf(di * (acc.x + hv.x) + b2[0], 0.f);
        float o1 = fmaxf(di * (acc.y + hv.y) + b2[1], 0.f);
        float h3 = o0 * W3[0] + o1 * W3[1];
        hs3[v] = di * h3;
    }
}

__global__ __launch_bounds__(TPB) void k_gather3(
    const int* __restrict__ off, const int* __restrict__ cnt,
    const int* __restrict__ ssrc, const float* __restrict__ hs3,
    const float* __restrict__ dinv, const float* __restrict__ b3,
    float* __restrict__ out, int n) {
    int t = blockIdx.x * TPB + threadIdx.x;
    int v = t >> 3, p = t & 7;
    if (v >= n) return;
    int base = off[v], c = cnt[v];
    float acc = 0.f;
    for (int i = p; i < c; i += 8) acc += hs3[ssrc[base + i]];
    acc += __shfl_xor(acc, 1); acc += __shfl_xor(acc, 2); acc += __shfl_xor(acc, 4);
    if (p == 0) {
        float di = dinv[v];
        float agg = di * (acc + hs3[v]) + b3[0];
        out[v] = 1.0f / (1.0f + __expf(-agg));
    }
}

extern "C" void kernel_launch(void* const* d_in, const int* in_sizes, int n_in,
                              void* d_out, int out_size, void* d_ws, size_t ws_size,
                              hipStream_t stream) {
    const float* x  = (const float*)d_in[0];
    const int* ei   = (const int*)d_in[1];
    const float* W1 = (const float*)d_in[2];
    const float* b1 = (const float*)d_in[3];
    const float* W2 = (const float*)d_in[4];
    const float* b2 = (const float*)d_in[5];
    const float* W3 = (const float*)d_in[6];
    const float* b3 = (const float*)d_in[7];
    float* out = (float*)d_out;

    const int N = in_sizes[0] / 128;
    const int E = in_sizes[1] / 2;
    const int* src = ei;
    const int* dst = ei + E;

    const int NS  = (E + CHUNK - 1) / CHUNK;  // 782 chunks
    const int NB  = (N + 255) >> 8;           // 391 buckets
    const int NBP = NB + 1;

    // ws carve (~29.7 MB). hs1/hs2/hs3 overlay the slab (dead after k_degree).
    char* w = (char*)d_ws;
    auto carve = [&](size_t bytes) { char* p = w; w += (bytes + 15) & ~(size_t)15; return p; };
    unsigned int* slab = (unsigned int*)carve((size_t)NS * CHUNK * 4);
    int* lstart        = (int*)carve((size_t)NS * NBP * 4);
    int* ssrc          = (int*)carve((size_t)NB * SLAB2 * 4);
    int* cnt           = (int*)carve((size_t)N * 4);
    int* off           = (int*)carve((size_t)N * 4);
    float* dinv        = (float*)carve((size_t)N * 4);
    float* hs1 = (float*)slab;                 // 4N floats (overlay)
    float* hs2 = hs1 + (size_t)4 * N;          // 2N
    float* hs3 = hs2 + (size_t)2 * N;          // N

    const int nbN4 = (4 * N + TPB - 1) / TPB;
    const int nbN8 = (8 * N + TPB - 1) / TPB;

    k_part   <<<NS, TPB, 0, stream>>>(src, dst, slab, lstart, NB, NBP, E);
    k_degree <<<NB, TPB, 0, stream>>>(slab, lstart, ssrc, cnt, off, dinv, NS, NBP, N);
    k_node1  <<<nbN4, TPB, 0, stream>>>(x, W1, dinv, hs1, N);
    k_gather1<<<nbN8, TPB, 0, stream>>>(off, cnt, ssrc, hs1, dinv, b1, W2, hs2, N);
    k_gather2<<<nbN8, TPB, 0, stream>>>(off, cnt, ssrc, hs2, dinv, b2, W3, hs3, N);
    k_gather3<<<nbN8, TPB, 0, stream>>>(off, cnt, ssrc, hs3, dinv, b3, out, N);
}